// Round 1
// baseline (1353.653 us; speedup 1.0000x reference)
//
#include <hip/hip_runtime.h>
#include <math.h>

#define NNODES 20000
#define NEDGES 640000
#define NS 128
#define ESZ 20
#define FW 384
#define CUT 5.0f
#define PI_F 3.14159265358979323846f

// -------- kernel 1: scalar_output = silu(ns@W1+b1)@W2+b2  -> d_ws --------
__global__ __launch_bounds__(128) void node_mlp(
    const float* __restrict__ ns, const float* __restrict__ W1,
    const float* __restrict__ b1, const float* __restrict__ W2,
    const float* __restrict__ b2, float* __restrict__ so) {
  __shared__ float row[NS];
  __shared__ float hid[NS];
  const int n = blockIdx.x;
  const int j = threadIdx.x;
  row[j] = ns[n * NS + j];
  __syncthreads();
  float acc = b1[j];
#pragma unroll 8
  for (int k = 0; k < NS; ++k) acc = fmaf(row[k], W1[k * NS + j], acc);
  // silu
  float h = acc / (1.0f + __expf(-acc));
  hid[j] = h;
  __syncthreads();
#pragma unroll
  for (int t = 0; t < 3; ++t) {
    const int col = j + NS * t;
    float a = b2[col];
#pragma unroll 8
    for (int k = 0; k < NS; ++k) a = fmaf(hid[k], W2[k * FW + col], a);
    so[n * FW + col] = a;
  }
}

// -------- kernel 2: init d_out with the residual (node states) --------
__global__ __launch_bounds__(256) void copy_init(
    const float4* __restrict__ ns4, const float4* __restrict__ nsv4,
    float4* __restrict__ out4) {
  const int i = blockIdx.x * blockDim.x + threadIdx.x;
  const int n0 = NNODES * NS / 4;        // 640000 float4 (scalar part)
  const int ntot = NNODES * 4 * NS / 4;  // 2560000 float4 total
  if (i < n0) {
    out4[i] = ns4[i];
  } else if (i < ntot) {
    out4[i] = nsv4[i - n0];
  }
}

// -------- kernel 3: per-edge fused filter + gate + scatter --------
__global__ __launch_bounds__(128) void edge_kernel(
    const float* __restrict__ edge_state, const float* __restrict__ edge_vector,
    const float* __restrict__ edge_distance, const int* __restrict__ edges,
    const float* __restrict__ Wf, const float* __restrict__ bf,
    const float* __restrict__ so, const float* __restrict__ ns,
    const float* __restrict__ nsv, float* __restrict__ out0,
    float* __restrict__ out1) {
  const int j = threadIdx.x;
  for (int e = blockIdx.x; e < NEDGES; e += gridDim.x) {
    const int src = edges[2 * e];
    const int dst = edges[2 * e + 1];

    float es[ESZ];
    const float* esp = edge_state + (size_t)e * ESZ;
#pragma unroll
    for (int k = 0; k < ESZ; ++k) es[k] = esp[k];

    const float d = edge_distance[e];
    const float cut = (d < CUT) ? 0.5f * (__cosf(PI_F * d * (1.0f / CUT)) + 1.0f) : 0.0f;

    const float ev0 = edge_vector[3 * e + 0];
    const float ev1 = edge_vector[3 * e + 1];
    const float ev2 = edge_vector[3 * e + 2];
    const float nrm = sqrtf(ev0 * ev0 + ev1 * ev1 + ev2 * ev2);
    const float inv = 1.0f / fmaxf(nrm, 1e-12f);
    const float env0 = ev0 * inv, env1 = ev1 * inv, env2 = ev2 * inv;

    // filter_output for this thread's 3 columns (j, j+128, j+256)
    float fo[3];
#pragma unroll
    for (int t = 0; t < 3; ++t) {
      const int col = j + NS * t;
      float a = bf[col];
#pragma unroll
      for (int k = 0; k < ESZ; ++k) a = fmaf(es[k], Wf[k * FW + col], a);
      fo[t] = a * cut * so[(size_t)src * FW + col];
    }

    // scalar message
    const float nsval = ns[(size_t)src * NS + j];
    atomicAdd(out0 + (size_t)dst * NS + j, nsval * fo[2]);

    // vector messages
    const float m0 = nsv[((size_t)src * 3 + 0) * NS + j] * fo[0] + fo[1] * env0;
    const float m1 = nsv[((size_t)src * 3 + 1) * NS + j] * fo[0] + fo[1] * env1;
    const float m2 = nsv[((size_t)src * 3 + 2) * NS + j] * fo[0] + fo[1] * env2;
    atomicAdd(out1 + ((size_t)dst * 3 + 0) * NS + j, m0);
    atomicAdd(out1 + ((size_t)dst * 3 + 1) * NS + j, m1);
    atomicAdd(out1 + ((size_t)dst * 3 + 2) * NS + j, m2);
  }
}

extern "C" void kernel_launch(void* const* d_in, const int* in_sizes, int n_in,
                              void* d_out, int out_size, void* d_ws, size_t ws_size,
                              hipStream_t stream) {
  const float* node_state_scalar = (const float*)d_in[0];
  const float* node_state_vector = (const float*)d_in[1];
  const float* edge_state        = (const float*)d_in[2];
  const float* edge_vector       = (const float*)d_in[3];
  const float* edge_distance     = (const float*)d_in[4];
  const int*   edges             = (const int*)d_in[5];
  const float* W_filter          = (const float*)d_in[6];
  const float* b_filter          = (const float*)d_in[7];
  const float* W1                = (const float*)d_in[8];
  const float* b1                = (const float*)d_in[9];
  const float* W2                = (const float*)d_in[10];
  const float* b2                = (const float*)d_in[11];

  float* out0 = (float*)d_out;                       // (20000,128)
  float* out1 = (float*)d_out + (size_t)NNODES * NS; // (20000,3,128)
  float* so   = (float*)d_ws;                        // (20000,384) scalar_output

  // 1. node MLP -> scalar_output in workspace
  node_mlp<<<NNODES, 128, 0, stream>>>(node_state_scalar, W1, b1, W2, b2, so);

  // 2. init output with residual
  {
    const int ntot4 = NNODES * 4 * NS / 4;  // 2,560,000 float4
    const int blocks = (ntot4 + 255) / 256;
    copy_init<<<blocks, 256, 0, stream>>>((const float4*)node_state_scalar,
                                          (const float4*)node_state_vector,
                                          (float4*)d_out);
  }

  // 3. fused edge kernel with atomic scatter
  edge_kernel<<<16384, 128, 0, stream>>>(edge_state, edge_vector, edge_distance,
                                         edges, W_filter, b_filter, so,
                                         node_state_scalar, node_state_vector,
                                         out0, out1);
}

// Round 3
// 645.161 us; speedup vs baseline: 2.0982x; 2.0982x over previous
//
#include <hip/hip_runtime.h>
#include <math.h>

#define NNODES 20000
#define NEDGES 640000
#define NS 128
#define ESZ 20
#define FW 384
#define CUT 5.0f
#define PI_F 3.14159265358979323846f
#define TM 32  // nodes per block in node_mlp

// -------- node MLP: so = silu(ns@W1+b1)@W2+b2, 32 nodes/block --------
__global__ __launch_bounds__(256) void node_mlp(
    const float* __restrict__ ns, const float* __restrict__ W1,
    const float* __restrict__ b1, const float* __restrict__ W2,
    const float* __restrict__ b2, float* __restrict__ so) {
  __shared__ float in_s[TM][NS];   // 16 KB
  __shared__ float hid_s[TM][NS];  // 16 KB
  const int t = threadIdx.x;
  const int n0 = blockIdx.x * TM;
  // cooperative float4 load of 32 input rows
  {
    const float4* src4 = (const float4*)(ns + (size_t)n0 * NS);
    float4* dst4 = (float4*)in_s;
    for (int idx = t; idx < TM * NS / 4; idx += 256) dst4[idx] = src4[idx];
  }
  __syncthreads();
  const int j = t & 127;
  const int half = t >> 7;  // 0/1 -> nodes [0,16) / [16,32)
  // ---- stage 1: hidden[m][j] for 16 nodes ----
  {
    float acc[16];
#pragma unroll
    for (int m = 0; m < 16; ++m) acc[m] = b1[j];
    for (int k = 0; k < NS; k += 4) {
      const float w0 = W1[(k + 0) * NS + j];
      const float w1 = W1[(k + 1) * NS + j];
      const float w2 = W1[(k + 2) * NS + j];
      const float w3 = W1[(k + 3) * NS + j];
#pragma unroll
      for (int m = 0; m < 16; ++m) {
        const float4 iv = *(const float4*)&in_s[half * 16 + m][k];
        acc[m] = fmaf(iv.x, w0, acc[m]);
        acc[m] = fmaf(iv.y, w1, acc[m]);
        acc[m] = fmaf(iv.z, w2, acc[m]);
        acc[m] = fmaf(iv.w, w3, acc[m]);
      }
    }
#pragma unroll
    for (int m = 0; m < 16; ++m) {
      const float a = acc[m];
      hid_s[half * 16 + m][j] = a / (1.0f + __expf(-a));
    }
  }
  __syncthreads();
  // ---- stage 2: 3 output cols (j, j+128, j+256) for 16 nodes ----
  {
    float o0[16], o1[16], o2[16];
    const float bb0 = b2[j], bb1 = b2[j + NS], bb2 = b2[j + 2 * NS];
#pragma unroll
    for (int m = 0; m < 16; ++m) { o0[m] = bb0; o1[m] = bb1; o2[m] = bb2; }
    for (int k = 0; k < NS; k += 4) {
      float wa[4], wb[4], wc[4];
#pragma unroll
      for (int kk = 0; kk < 4; ++kk) {
        wa[kk] = W2[(k + kk) * FW + j];
        wb[kk] = W2[(k + kk) * FW + j + NS];
        wc[kk] = W2[(k + kk) * FW + j + 2 * NS];
      }
#pragma unroll
      for (int m = 0; m < 16; ++m) {
        const float4 hv = *(const float4*)&hid_s[half * 16 + m][k];
        o0[m] = fmaf(hv.x, wa[0], o0[m]); o0[m] = fmaf(hv.y, wa[1], o0[m]);
        o0[m] = fmaf(hv.z, wa[2], o0[m]); o0[m] = fmaf(hv.w, wa[3], o0[m]);
        o1[m] = fmaf(hv.x, wb[0], o1[m]); o1[m] = fmaf(hv.y, wb[1], o1[m]);
        o1[m] = fmaf(hv.z, wb[2], o1[m]); o1[m] = fmaf(hv.w, wb[3], o1[m]);
        o2[m] = fmaf(hv.x, wc[0], o2[m]); o2[m] = fmaf(hv.y, wc[1], o2[m]);
        o2[m] = fmaf(hv.z, wc[2], o2[m]); o2[m] = fmaf(hv.w, wc[3], o2[m]);
      }
    }
#pragma unroll
    for (int m = 0; m < 16; ++m) {
      const size_t row = (size_t)(n0 + half * 16 + m) * FW;
      so[row + j] = o0[m];
      so[row + j + NS] = o1[m];
      so[row + j + 2 * NS] = o2[m];
    }
  }
}

// -------- sort-by-dst machinery --------
__global__ __launch_bounds__(256) void zero_cnt(int* __restrict__ cnt) {
  const int i = blockIdx.x * 256 + threadIdx.x;
  if (i < NNODES) cnt[i] = 0;
}

__global__ __launch_bounds__(256) void hist_dst(const int* __restrict__ edges,
                                                int* __restrict__ cnt) {
  const int e = blockIdx.x * 256 + threadIdx.x;
  if (e < NEDGES) atomicAdd(&cnt[edges[2 * e + 1]], 1);
}

__global__ __launch_bounds__(1024) void scan_counts(const int* __restrict__ cnt,
                                                    int* __restrict__ offsets,
                                                    int* __restrict__ cursor) {
  __shared__ int psum[1024];
  const int t = threadIdx.x;
  const int base = t * 20;
  int local[20];
  int s = 0;
#pragma unroll
  for (int k = 0; k < 20; ++k) {
    const int idx = base + k;
    const int v = (idx < NNODES) ? cnt[idx] : 0;
    local[k] = s;  // exclusive within chunk
    s += v;
  }
  psum[t] = s;
  __syncthreads();
  for (int off = 1; off < 1024; off <<= 1) {
    const int v = (t >= off) ? psum[t - off] : 0;
    __syncthreads();
    psum[t] += v;
    __syncthreads();
  }
  const int pre = (t > 0) ? psum[t - 1] : 0;
#pragma unroll
  for (int k = 0; k < 20; ++k) {
    const int idx = base + k;
    if (idx < NNODES) {
      offsets[idx] = pre + local[k];
      cursor[idx] = pre + local[k];
    }
  }
  if (t == 1023) offsets[NNODES] = psum[1023];
}

__global__ __launch_bounds__(256) void scatter_edges(const int* __restrict__ edges,
                                                     int* __restrict__ cursor,
                                                     int* __restrict__ elist) {
  const int e = blockIdx.x * 256 + threadIdx.x;
  if (e < NEDGES) {
    const int pos = atomicAdd(&cursor[edges[2 * e + 1]], 1);
    elist[pos] = e;
  }
}

// -------- per-dst accumulation (no atomics) --------
__global__ __launch_bounds__(128) void accum(
    const int* __restrict__ elist, const int* __restrict__ offsets,
    const int* __restrict__ edges, const float* __restrict__ edge_state,
    const float* __restrict__ edge_vector, const float* __restrict__ edge_distance,
    const float* __restrict__ Wf, const float* __restrict__ bf,
    const float* __restrict__ so, const float* __restrict__ ns,
    const float* __restrict__ nsv, float* __restrict__ out0,
    float* __restrict__ out1) {
  const int n = blockIdx.x;
  const int j = threadIdx.x;
  const int beg = offsets[n];
  const int end = offsets[n + 1];

  // W_filter columns for this thread, register-resident across all edges
  float wf0[ESZ], wf1[ESZ], wf2[ESZ];
#pragma unroll
  for (int k = 0; k < ESZ; ++k) {
    wf0[k] = Wf[k * FW + j];
    wf1[k] = Wf[k * FW + j + NS];
    wf2[k] = Wf[k * FW + j + 2 * NS];
  }
  const float bf0 = bf[j], bf1 = bf[j + NS], bf2 = bf[j + 2 * NS];

  float accs = 0.0f, av0 = 0.0f, av1 = 0.0f, av2 = 0.0f;

  for (int i = beg; i < end; ++i) {
    const int e = __builtin_amdgcn_readfirstlane(elist[i]);
    const int src = __builtin_amdgcn_readfirstlane(edges[2 * e]);

    const float d = edge_distance[e];
    const float cut = (d < CUT) ? 0.5f * (__cosf(PI_F * d * (1.0f / CUT)) + 1.0f) : 0.0f;

    const float ev0 = edge_vector[3 * e + 0];
    const float ev1 = edge_vector[3 * e + 1];
    const float ev2 = edge_vector[3 * e + 2];
    const float nrm = sqrtf(ev0 * ev0 + ev1 * ev1 + ev2 * ev2);
    const float inv = 1.0f / fmaxf(nrm, 1e-12f);
    const float env0 = ev0 * inv, env1 = ev1 * inv, env2 = ev2 * inv;

    const float* __restrict__ esp = edge_state + (size_t)e * ESZ;
    float fo0 = bf0, fo1 = bf1, fo2 = bf2;
#pragma unroll
    for (int k = 0; k < ESZ; ++k) {
      const float es = esp[k];
      fo0 = fmaf(es, wf0[k], fo0);
      fo1 = fmaf(es, wf1[k], fo1);
      fo2 = fmaf(es, wf2[k], fo2);
    }

    const float* __restrict__ sop = so + (size_t)src * FW;
    fo0 *= cut * sop[j];
    fo1 *= cut * sop[j + NS];
    fo2 *= cut * sop[j + 2 * NS];

    accs = fmaf(ns[(size_t)src * NS + j], fo2, accs);
    const float* __restrict__ nvp = nsv + (size_t)src * 3 * NS;
    av0 = fmaf(nvp[j], fo0, av0);           av0 = fmaf(fo1, env0, av0);
    av1 = fmaf(nvp[NS + j], fo0, av1);      av1 = fmaf(fo1, env1, av1);
    av2 = fmaf(nvp[2 * NS + j], fo0, av2);  av2 = fmaf(fo1, env2, av2);
  }

  out0[(size_t)n * NS + j] = ns[(size_t)n * NS + j] + accs;
  float* __restrict__ o1 = out1 + (size_t)n * 3 * NS;
  const float* __restrict__ nvd = nsv + (size_t)n * 3 * NS;
  o1[j] = nvd[j] + av0;
  o1[NS + j] = nvd[NS + j] + av1;
  o1[2 * NS + j] = nvd[2 * NS + j] + av2;
}

extern "C" void kernel_launch(void* const* d_in, const int* in_sizes, int n_in,
                              void* d_out, int out_size, void* d_ws, size_t ws_size,
                              hipStream_t stream) {
  const float* node_state_scalar = (const float*)d_in[0];
  const float* node_state_vector = (const float*)d_in[1];
  const float* edge_state        = (const float*)d_in[2];
  const float* edge_vector       = (const float*)d_in[3];
  const float* edge_distance     = (const float*)d_in[4];
  const int*   edges             = (const int*)d_in[5];
  const float* W_filter          = (const float*)d_in[6];
  const float* b_filter          = (const float*)d_in[7];
  const float* W1                = (const float*)d_in[8];
  const float* b1                = (const float*)d_in[9];
  const float* W2                = (const float*)d_in[10];
  const float* b2                = (const float*)d_in[11];

  float* out0 = (float*)d_out;                       // (20000,128)
  float* out1 = (float*)d_out + (size_t)NNODES * NS; // (20000,3,128)

  // workspace layout
  float* so    = (float*)d_ws;                        // 20000*384 floats
  int* elist   = (int*)(so + (size_t)NNODES * FW);    // 640000
  int* offsets = elist + NEDGES;                      // 20001
  int* cursor  = offsets + (NNODES + 1);              // 20000
  int* cnt     = cursor + NNODES;                     // 20000

  // sort edges by dst
  zero_cnt<<<(NNODES + 255) / 256, 256, 0, stream>>>(cnt);
  hist_dst<<<(NEDGES + 255) / 256, 256, 0, stream>>>(edges, cnt);
  scan_counts<<<1, 1024, 0, stream>>>(cnt, offsets, cursor);
  scatter_edges<<<(NEDGES + 255) / 256, 256, 0, stream>>>(edges, cursor, elist);

  // node MLP
  node_mlp<<<NNODES / TM, 256, 0, stream>>>(node_state_scalar, W1, b1, W2, b2, so);

  // per-dst accumulation, residual fused
  accum<<<NNODES, 128, 0, stream>>>(elist, offsets, edges, edge_state, edge_vector,
                                    edge_distance, W_filter, b_filter, so,
                                    node_state_scalar, node_state_vector,
                                    out0, out1);
}